// Round 9
// baseline (386.595 us; speedup 1.0000x reference)
//
#include <hip/hip_runtime.h>

// Affine_Linear_Abla_Quat — bf16 MFMA, v6: double-buffered LDS chunk pipeline.
// 256 blocks x 8 chunks of Gp=16 pairs. Per chunk: issue next chunk's J/X
// loads -> GEMM current chunk (HBM latency hides under ~3000cyc of k-loop) ->
// store Y -> quat-produce next chunk into the other TT buffer -> barrier.
// LDS 2x73.7KB = 147KB -> 1 block/CU, LB(512,2) -> VGPR cap 256 (no spill).
// Learned: v4 (cap 170 + sched_barrier) spilled; v5 (8 waves/SIMD, VGPR 28)
// killed memory ILP. This keeps v3's tile with latency overlap + big reg cap.

typedef __bf16 bf16_t;
typedef __attribute__((ext_vector_type(8))) __bf16 bf16x8;
typedef __attribute__((ext_vector_type(4))) __bf16 bf16x4;
typedef __attribute__((ext_vector_type(4))) float f32x4;

constexpr int Dd  = 256;   // D == F
constexpr int Gp  = 16;    // pairs per chunk -> M = 48
constexpr int NCH = 8;     // chunks per block
constexpr int TPB = 512;   // 8 waves

__device__ __forceinline__ bf16_t to_bf16(float f) {
    unsigned u = __builtin_bit_cast(unsigned, f);
    u += 0x7FFFu + ((u >> 16) & 1u);          // RNE
    unsigned short h = (unsigned short)(u >> 16);
    return __builtin_bit_cast(bf16_t, h);
}

// swizzled element index into a TT buffer: row-major [48][768], 16B granule XOR (row&7)
__device__ __forceinline__ int swz(int row, int k) {
    return row * 768 + (k ^ ((row & 7) << 3));
}

// ---- prologue: A,B,C (f32 256x256) -> W bf16 [3][256][256] in d_ws ----
__global__ __launch_bounds__(256)
void convert_w_kernel(const float* __restrict__ A, const float* __restrict__ B,
                      const float* __restrict__ C, bf16_t* __restrict__ W)
{
    const int e4 = (blockIdx.x * 256 + threadIdx.x) * 4;
    const float* src;
    if (e4 < 65536)        src = A + e4;
    else if (e4 < 131072)  src = B + (e4 - 65536);
    else                   src = C + (e4 - 131072);
    const float4 v = *reinterpret_cast<const float4*>(src);
    bf16x4 o;
    o[0] = to_bf16(v.x); o[1] = to_bf16(v.y); o[2] = to_bf16(v.z); o[3] = to_bf16(v.w);
    *reinterpret_cast<bf16x4*>(W + e4) = o;
}

// ------------------------------ main kernel ------------------------------
__global__ __launch_bounds__(TPB, 2)
void alaq_mfma_kernel(const float* __restrict__ X, const float* __restrict__ J,
                      const bf16_t* __restrict__ W, float* __restrict__ Y)
{
    __shared__ bf16_t TT[2][48 * 768];   // 147,456 B -> 1 block/CU

    const int tid = threadIdx.x;
    const long pair0 = (long)blockIdx.x * (Gp * NCH);

    const int w  = tid >> 6;          // wave 0..7, owns f-strips {2w, 2w+1}
    const int l  = tid & 63;
    const int lr = l & 15;
    const int lq = l >> 4;

    const int f0 = (2 * w) * 16 + lr;
    const bf16_t* Wf0 = W + f0 * 256 + (lq << 3);
    const bf16_t* Wf1 = Wf0 + 16 * 256;
    const int swzmask = (lr & 7) << 3;

    float4 qv[8];
    float  xv[8][3];

    // ---- prologue: load + produce chunk 0 into TT[0] ----
    {
        const long eb = pair0 * Dd;
        #pragma unroll
        for (int rr = 0; rr < 8; ++rr) {
            const long base = eb + rr * TPB + tid;
            qv[rr] = *reinterpret_cast<const float4*>(J + base * 4);
            const float* xp = X + base * 3;
            xv[rr][0] = xp[0]; xv[rr][1] = xp[1]; xv[rr][2] = xp[2];
        }
        #pragma unroll
        for (int rr = 0; rr < 8; ++rr) {
            const int idx = rr * TPB + tid;
            const int p = idx >> 8;
            const int e = idx & 255;
            const float4 q = qv[rr];
            const float x0 = xv[rr][0], x1 = xv[rr][1], x2 = xv[rr][2];

            const float nsq = q.x*q.x + q.y*q.y + q.z*q.z + q.w*q.w;
            const float inv = 1.0f / fmaxf(sqrtf(nsq), 1e-12f);
            const float qx = q.x*inv, qy = q.y*inv, qz = q.z*inv, qw = q.w*inv;
            const float s = 2.0f / (qw*qw + qx*qx + qy*qy + qz*qz);

            const float r00 = 1.0f - s*(qy*qy + qz*qz);
            const float r01 = s*(qx*qy - qz*qw);
            const float r02 = s*(qx*qz + qy*qw);
            const float r10 = s*(qx*qy + qz*qw);
            const float r11 = 1.0f - s*(qx*qx + qz*qz);
            const float r12 = s*(qy*qz - qx*qw);
            const float r20 = s*(qx*qz - qy*qw);
            const float r21 = s*(qy*qz + qx*qw);
            const float r22 = 1.0f - s*(qx*qx + qy*qy);

            const float rt0 = r00*x0 + r10*x1 + r20*x2;
            const float rt1 = r01*x0 + r11*x1 + r21*x2;
            const float rt2 = r02*x0 + r12*x1 + r22*x2;

            const int row = p * 3;
            bf16_t* tt = TT[0];
            tt[swz(row    ,       e)] = to_bf16(r00*rt0 + r01*rt1);
            tt[swz(row + 1,       e)] = to_bf16(r10*rt0 + r11*rt1);
            tt[swz(row + 2,       e)] = to_bf16(r20*rt0 + r21*rt1);
            tt[swz(row    , 256 + e)] = to_bf16(r01*rt0 - r00*rt1);
            tt[swz(row + 1, 256 + e)] = to_bf16(r11*rt0 - r10*rt1);
            tt[swz(row + 2, 256 + e)] = to_bf16(r21*rt0 - r20*rt1);
            tt[swz(row    , 512 + e)] = to_bf16(r02*rt2);
            tt[swz(row + 1, 512 + e)] = to_bf16(r12*rt2);
            tt[swz(row + 2, 512 + e)] = to_bf16(r22*rt2);
        }
    }
    __syncthreads();

    int cur = 0;
    for (int t = 0; t < NCH; ++t) {
        // ---- issue next chunk's global loads; consumed after the k-loop ----
        if (t + 1 < NCH) {
            const long eb = (pair0 + (long)(t + 1) * Gp) * Dd;
            #pragma unroll
            for (int rr = 0; rr < 8; ++rr) {
                const long base = eb + rr * TPB + tid;
                qv[rr] = *reinterpret_cast<const float4*>(J + base * 4);
                const float* xp = X + base * 3;
                xv[rr][0] = xp[0]; xv[rr][1] = xp[1]; xv[rr][2] = xp[2];
            }
        }

        // ---- GEMM on TT[cur] ----
        const bf16_t* tt = TT[cur];
        f32x4 acc[3][2] = {};

        #pragma unroll
        for (int k0 = 0; k0 < 24; ++k0) {
            const int term = k0 >> 3;
            const int eb   = (k0 & 7) << 5;
            const bf16x8 b0 = *reinterpret_cast<const bf16x8*>(Wf0 + (term << 16) + eb);
            const bf16x8 b1 = *reinterpret_cast<const bf16x8*>(Wf1 + (term << 16) + eb);

            const int kswz = (((k0 << 5) + (lq << 3)) ^ swzmask);
            const bf16x8 a0 = *reinterpret_cast<const bf16x8*>(&tt[      lr  * 768 + kswz]);
            const bf16x8 a1 = *reinterpret_cast<const bf16x8*>(&tt[(16 + lr) * 768 + kswz]);
            const bf16x8 a2 = *reinterpret_cast<const bf16x8*>(&tt[(32 + lr) * 768 + kswz]);

            acc[0][0] = __builtin_amdgcn_mfma_f32_16x16x32_bf16(a0, b0, acc[0][0], 0, 0, 0);
            acc[1][0] = __builtin_amdgcn_mfma_f32_16x16x32_bf16(a1, b0, acc[1][0], 0, 0, 0);
            acc[2][0] = __builtin_amdgcn_mfma_f32_16x16x32_bf16(a2, b0, acc[2][0], 0, 0, 0);
            acc[0][1] = __builtin_amdgcn_mfma_f32_16x16x32_bf16(a0, b1, acc[0][1], 0, 0, 0);
            acc[1][1] = __builtin_amdgcn_mfma_f32_16x16x32_bf16(a1, b1, acc[1][1], 0, 0, 0);
            acc[2][1] = __builtin_amdgcn_mfma_f32_16x16x32_bf16(a2, b1, acc[2][1], 0, 0, 0);
        }

        // ---- store Y for chunk t ----
        const long pbase = pair0 + (long)t * Gp;
        #pragma unroll
        for (int mi = 0; mi < 3; ++mi) {
            #pragma unroll
            for (int ni = 0; ni < 2; ++ni) {
                const int f = (2 * w + ni) * 16 + lr;
                #pragma unroll
                for (int r = 0; r < 4; ++r) {
                    const int m = mi * 16 + lq * 4 + r;
                    const int p = m / 3;
                    const int i = m - p * 3;
                    Y[(pbase + p) * 768 + f * 3 + i] = acc[mi][ni][r];
                }
            }
        }

        // ---- produce chunk t+1 into the other buffer; then one barrier ----
        if (t + 1 < NCH) {
            bf16_t* ttn = TT[cur ^ 1];
            #pragma unroll
            for (int rr = 0; rr < 8; ++rr) {
                const int idx = rr * TPB + tid;
                const int p = idx >> 8;
                const int e = idx & 255;
                const float4 q = qv[rr];
                const float x0 = xv[rr][0], x1 = xv[rr][1], x2 = xv[rr][2];

                const float nsq = q.x*q.x + q.y*q.y + q.z*q.z + q.w*q.w;
                const float inv = 1.0f / fmaxf(sqrtf(nsq), 1e-12f);
                const float qx = q.x*inv, qy = q.y*inv, qz = q.z*inv, qw = q.w*inv;
                const float s = 2.0f / (qw*qw + qx*qx + qy*qy + qz*qz);

                const float r00 = 1.0f - s*(qy*qy + qz*qz);
                const float r01 = s*(qx*qy - qz*qw);
                const float r02 = s*(qx*qz + qy*qw);
                const float r10 = s*(qx*qy + qz*qw);
                const float r11 = 1.0f - s*(qx*qx + qz*qz);
                const float r12 = s*(qy*qz - qx*qw);
                const float r20 = s*(qx*qz - qy*qw);
                const float r21 = s*(qy*qz + qx*qw);
                const float r22 = 1.0f - s*(qx*qx + qy*qy);

                const float rt0 = r00*x0 + r10*x1 + r20*x2;
                const float rt1 = r01*x0 + r11*x1 + r21*x2;
                const float rt2 = r02*x0 + r12*x1 + r22*x2;

                const int row = p * 3;
                ttn[swz(row    ,       e)] = to_bf16(r00*rt0 + r01*rt1);
                ttn[swz(row + 1,       e)] = to_bf16(r10*rt0 + r11*rt1);
                ttn[swz(row + 2,       e)] = to_bf16(r20*rt0 + r21*rt1);
                ttn[swz(row    , 256 + e)] = to_bf16(r01*rt0 - r00*rt1);
                ttn[swz(row + 1, 256 + e)] = to_bf16(r11*rt0 - r10*rt1);
                ttn[swz(row + 2, 256 + e)] = to_bf16(r21*rt0 - r20*rt1);
                ttn[swz(row    , 512 + e)] = to_bf16(r02*rt2);
                ttn[swz(row + 1, 512 + e)] = to_bf16(r12*rt2);
                ttn[swz(row + 2, 512 + e)] = to_bf16(r22*rt2);
            }
        }
        __syncthreads();
        cur ^= 1;
    }
}

extern "C" void kernel_launch(void* const* d_in, const int* in_sizes, int n_in,
                              void* d_out, int out_size, void* d_ws, size_t ws_size,
                              hipStream_t stream) {
    const float* X  = (const float*)d_in[0];
    const float* J  = (const float*)d_in[1];
    const float* A  = (const float*)d_in[2];
    const float* B  = (const float*)d_in[3];
    const float* Cm = (const float*)d_in[4];
    float* Y = (float*)d_out;
    bf16_t* W = (bf16_t*)d_ws;    // 393,216 B

    convert_w_kernel<<<192, 256, 0, stream>>>(A, B, Cm, W);

    const int nbn = in_sizes[1] / (Dd * 4);       // 32768
    const int blocks = nbn / (Gp * NCH);          // 256
    alaq_mfma_kernel<<<blocks, TPB, 0, stream>>>(X, J, W, Y);
}

// Round 10
// 151.578 us; speedup vs baseline: 2.5505x; 2.5505x over previous
//
#include <hip/hip_runtime.h>

// Affine_Linear_Abla_Quat — bf16 MFMA, v7 = v3 + surgical lookahead.
// Learned: v4/v6 cross-k-loop register payloads spill (WRITE 98->314/698 MB);
// v5 high-occupancy/low-VGPR kills memory ILP; v3 (144us, VGPR 52) has zero
// lookahead. v7 adds ONLY short-live-range prefetch:
//   phase 1: load-all-8 -> sched_barrier -> compute-all-8
//   phase 2: per-k0 rotation: issue loads(k0+1) -> sched_barrier -> MFMA(k0)
// Gp=16, TPB=512, LDS 73.7KB, LB(512,4): 2 blocks/CU, VGPR cap 128.

typedef __bf16 bf16_t;
typedef __attribute__((ext_vector_type(8))) __bf16 bf16x8;
typedef __attribute__((ext_vector_type(4))) __bf16 bf16x4;
typedef __attribute__((ext_vector_type(4))) float f32x4;

constexpr int Dd  = 256;   // D == F
constexpr int Gp  = 16;    // pairs per block -> M = 48
constexpr int TPB = 512;   // 8 waves

__device__ __forceinline__ bf16_t to_bf16(float f) {
    unsigned u = __builtin_bit_cast(unsigned, f);
    u += 0x7FFFu + ((u >> 16) & 1u);          // RNE
    unsigned short h = (unsigned short)(u >> 16);
    return __builtin_bit_cast(bf16_t, h);
}

// swizzled element index into TT: row-major [48][768], 16B granule XOR (row&7)
__device__ __forceinline__ int swz(int row, int k) {
    return row * 768 + (k ^ ((row & 7) << 3));
}

// ---- prologue: A,B,C (f32 256x256) -> W bf16 [3][256][256] in d_ws ----
__global__ __launch_bounds__(256)
void convert_w_kernel(const float* __restrict__ A, const float* __restrict__ B,
                      const float* __restrict__ C, bf16_t* __restrict__ W)
{
    const int e4 = (blockIdx.x * 256 + threadIdx.x) * 4;
    const float* src;
    if (e4 < 65536)        src = A + e4;
    else if (e4 < 131072)  src = B + (e4 - 65536);
    else                   src = C + (e4 - 131072);
    const float4 v = *reinterpret_cast<const float4*>(src);
    bf16x4 o;
    o[0] = to_bf16(v.x); o[1] = to_bf16(v.y); o[2] = to_bf16(v.z); o[3] = to_bf16(v.w);
    *reinterpret_cast<bf16x4*>(W + e4) = o;
}

// ------------------------------ main kernel ------------------------------
__global__ __launch_bounds__(TPB, 4)
void alaq_mfma_kernel(const float* __restrict__ X, const float* __restrict__ J,
                      const bf16_t* __restrict__ W, float* __restrict__ Y)
{
    __shared__ bf16_t TT[48 * 768];   // 73,728 B -> 2 blocks/CU

    const int tid = threadIdx.x;
    const long bn0 = (long)blockIdx.x * Gp;
    const long ebase = bn0 * Dd;

    // ---------------- Phase 1: batch loads, pin, then compute ----------------
    float4 qv[8];
    float  xv[8][3];
    #pragma unroll
    for (int rr = 0; rr < 8; ++rr) {
        const long base = ebase + rr * TPB + tid;
        qv[rr] = *reinterpret_cast<const float4*>(J + base * 4);
        const float* xp = X + base * 3;
        xv[rr][0] = xp[0]; xv[rr][1] = xp[1]; xv[rr][2] = xp[2];
    }
    __builtin_amdgcn_sched_barrier(0);   // keep all 32 loads issued up front

    #pragma unroll
    for (int rr = 0; rr < 8; ++rr) {
        const int idx = rr * TPB + tid;
        const int p = idx >> 8;
        const int e = idx & 255;

        const float4 q = qv[rr];
        const float x0 = xv[rr][0], x1 = xv[rr][1], x2 = xv[rr][2];

        const float nsq = q.x*q.x + q.y*q.y + q.z*q.z + q.w*q.w;
        const float inv = 1.0f / fmaxf(sqrtf(nsq), 1e-12f);
        const float qx = q.x*inv, qy = q.y*inv, qz = q.z*inv, qw = q.w*inv;
        const float s = 2.0f / (qw*qw + qx*qx + qy*qy + qz*qz);

        const float r00 = 1.0f - s*(qy*qy + qz*qz);
        const float r01 = s*(qx*qy - qz*qw);
        const float r02 = s*(qx*qz + qy*qw);
        const float r10 = s*(qx*qy + qz*qw);
        const float r11 = 1.0f - s*(qx*qx + qz*qz);
        const float r12 = s*(qy*qz - qx*qw);
        const float r20 = s*(qx*qz - qy*qw);
        const float r21 = s*(qy*qz + qx*qw);
        const float r22 = 1.0f - s*(qx*qx + qy*qy);

        const float rt0 = r00*x0 + r10*x1 + r20*x2;
        const float rt1 = r01*x0 + r11*x1 + r21*x2;
        const float rt2 = r02*x0 + r12*x1 + r22*x2;

        const int row = p * 3;
        TT[swz(row    ,       e)] = to_bf16(r00*rt0 + r01*rt1);
        TT[swz(row + 1,       e)] = to_bf16(r10*rt0 + r11*rt1);
        TT[swz(row + 2,       e)] = to_bf16(r20*rt0 + r21*rt1);
        TT[swz(row    , 256 + e)] = to_bf16(r01*rt0 - r00*rt1);
        TT[swz(row + 1, 256 + e)] = to_bf16(r11*rt0 - r10*rt1);
        TT[swz(row + 2, 256 + e)] = to_bf16(r21*rt0 - r20*rt1);
        TT[swz(row    , 512 + e)] = to_bf16(r02*rt2);
        TT[swz(row + 1, 512 + e)] = to_bf16(r12*rt2);
        TT[swz(row + 2, 512 + e)] = to_bf16(r22*rt2);
    }
    __syncthreads();

    // ---------------- Phase 2: MFMA GEMM with depth-1 rotation ----------------
    const int w  = tid >> 6;          // wave 0..7, owns f-strips {2w, 2w+1}
    const int l  = tid & 63;
    const int lr = l & 15;
    const int lq = l >> 4;

    f32x4 acc[3][2] = {};

    const int f0 = (2 * w) * 16 + lr;
    const bf16_t* Wf0 = W + f0 * 256 + (lq << 3);
    const bf16_t* Wf1 = Wf0 + 16 * 256;
    const int swzmask = (lr & 7) << 3;

    // fragment fetch for step k0 (compile-time k0 after unroll)
    auto FETCH_B0 = [&](int k0) -> bf16x8 {
        return *reinterpret_cast<const bf16x8*>(Wf0 + ((k0 >> 3) << 16) + ((k0 & 7) << 5));
    };
    auto FETCH_B1 = [&](int k0) -> bf16x8 {
        return *reinterpret_cast<const bf16x8*>(Wf1 + ((k0 >> 3) << 16) + ((k0 & 7) << 5));
    };
    auto FETCH_A = [&](int k0, int m16) -> bf16x8 {
        const int kswz = (((k0 << 5) + (lq << 3)) ^ swzmask);
        return *reinterpret_cast<const bf16x8*>(&TT[(m16 + lr) * 768 + kswz]);
    };

    bf16x8 b0c = FETCH_B0(0), b1c = FETCH_B1(0);
    bf16x8 a0c = FETCH_A(0, 0), a1c = FETCH_A(0, 16), a2c = FETCH_A(0, 32);

    #pragma unroll
    for (int k0 = 0; k0 < 24; ++k0) {
        bf16x8 b0n, b1n, a0n, a1n, a2n;
        if (k0 + 1 < 24) {
            b0n = FETCH_B0(k0 + 1);
            b1n = FETCH_B1(k0 + 1);
            a0n = FETCH_A(k0 + 1, 0);
            a1n = FETCH_A(k0 + 1, 16);
            a2n = FETCH_A(k0 + 1, 32);
        }
        __builtin_amdgcn_sched_barrier(0);   // loads(k0+1) issue before MFMAs(k0)

        acc[0][0] = __builtin_amdgcn_mfma_f32_16x16x32_bf16(a0c, b0c, acc[0][0], 0, 0, 0);
        acc[1][0] = __builtin_amdgcn_mfma_f32_16x16x32_bf16(a1c, b0c, acc[1][0], 0, 0, 0);
        acc[2][0] = __builtin_amdgcn_mfma_f32_16x16x32_bf16(a2c, b0c, acc[2][0], 0, 0, 0);
        acc[0][1] = __builtin_amdgcn_mfma_f32_16x16x32_bf16(a0c, b1c, acc[0][1], 0, 0, 0);
        acc[1][1] = __builtin_amdgcn_mfma_f32_16x16x32_bf16(a1c, b1c, acc[1][1], 0, 0, 0);
        acc[2][1] = __builtin_amdgcn_mfma_f32_16x16x32_bf16(a2c, b1c, acc[2][1], 0, 0, 0);

        b0c = b0n; b1c = b1n; a0c = a0n; a1c = a1n; a2c = a2n;
    }

    // ---------------- Epilogue ----------------
    #pragma unroll
    for (int mi = 0; mi < 3; ++mi) {
        #pragma unroll
        for (int ni = 0; ni < 2; ++ni) {
            const int f = (2 * w + ni) * 16 + lr;
            #pragma unroll
            for (int r = 0; r < 4; ++r) {
                const int m = mi * 16 + lq * 4 + r;
                const int p = m / 3;
                const int i = m - p * 3;
                Y[(bn0 + p) * 768 + f * 3 + i] = acc[mi][ni][r];
            }
        }
    }
}

extern "C" void kernel_launch(void* const* d_in, const int* in_sizes, int n_in,
                              void* d_out, int out_size, void* d_ws, size_t ws_size,
                              hipStream_t stream) {
    const float* X  = (const float*)d_in[0];
    const float* J  = (const float*)d_in[1];
    const float* A  = (const float*)d_in[2];
    const float* B  = (const float*)d_in[3];
    const float* Cm = (const float*)d_in[4];
    float* Y = (float*)d_out;
    bf16_t* W = (bf16_t*)d_ws;    // 393,216 B

    convert_w_kernel<<<192, 256, 0, stream>>>(A, B, Cm, W);

    const int nbn = in_sizes[1] / (Dd * 4);       // 32768
    const int blocks = nbn / Gp;                  // 2048
    alaq_mfma_kernel<<<blocks, TPB, 0, stream>>>(X, J, W, Y);
}